// Round 9
// baseline (2725.549 us; speedup 1.0000x reference)
//
#include <hip/hip_runtime.h>
#include <cstdint>
#include <cstddef>

#define NB 256
#define NS 512
#define NE 300
#define NH 512

using f32x4 = __attribute__((ext_vector_type(4))) float;
using s16x8 = __attribute__((ext_vector_type(8))) short;

static __device__ __forceinline__ unsigned short f2bf(float f) {
  unsigned u = __float_as_uint(f);
  u += 0x7FFFu + ((u >> 16) & 1u);
  return (unsigned short)(u >> 16);
}
static __device__ __forceinline__ float bf2f(unsigned short h) {
  return __uint_as_float(((unsigned)h) << 16);
}
static __device__ __forceinline__ float fast_tanh(float x) {
  float xc = fminf(fmaxf(x, -9.f), 9.f);
  float e = __expf(2.f * xc);
  return (e - 1.f) / (e + 1.f);
}
static __device__ __forceinline__ float sigm(float x) {
  return 1.f / (1.f + __expf(-x));
}

// ---------------- init: agent-scope zero of tagged h (tag 0 == valid h(0)) ----------------
__global__ void k_zero(unsigned* __restrict__ h_w) {
  int i = blockIdx.x * 256 + threadIdx.x;   // grid 64 -> 16384 threads; 1MB total
  unsigned long long* p = (unsigned long long*)(h_w + (size_t)i * 16);
  #pragma unroll
  for (int j = 0; j < 8; ++j)
    __hip_atomic_store(p + j, 0ull, __ATOMIC_RELAXED, __HIP_MEMORY_SCOPE_AGENT);
}

// ---------------- x_pre = tanh(embed_W[seq]) as bf16, layout [g_b][s][16][320] ----------------
__global__ __launch_bounds__(256) void k_xemb(const int* __restrict__ seq,
                                              const float* __restrict__ embed_W,
                                              unsigned short* __restrict__ x_pre) {
  const long long total = (long long)NB * NS * 40;   // tasks of 8 cols
  for (long long t = (long long)blockIdx.x * 256 + threadIdx.x; t < total;
       t += (long long)gridDim.x * 256) {
    int c = (int)(t % 40);
    long long p = t / 40;
    int s = (int)(p % NS);
    int b = (int)(p / NS);
    int g_b = b >> 4, r = b & 15;
    float vals[8];
    if (c < 38) {
      int id = seq[(size_t)b * NS + s];
      const float* ep = embed_W + (size_t)id * NE;
      if (c < 37) {
        f32x4 u0 = *(const f32x4*)(ep + c * 8);
        f32x4 u1 = *(const f32x4*)(ep + c * 8 + 4);
        vals[0]=u0[0];vals[1]=u0[1];vals[2]=u0[2];vals[3]=u0[3];
        vals[4]=u1[0];vals[5]=u1[1];vals[6]=u1[2];vals[7]=u1[3];
      } else {
        #pragma unroll
        for (int jj = 0; jj < 8; ++jj) { int cc = 296 + jj; vals[jj] = (cc < NE) ? ep[cc] : 0.f; }
      }
    } else {
      #pragma unroll
      for (int jj = 0; jj < 8; ++jj) vals[jj] = 0.f;
    }
    s16x8 pv;
    #pragma unroll
    for (int jj = 0; jj < 8; ++jj) pv[jj] = (short)f2bf(fast_tanh(vals[jj]));
    *(s16x8*)(x_pre + (((size_t)g_b * NS + s) * 16 + r) * 320 + c * 8) = pv;
  }
}

// ---------------- a = tanh(tanh(class_emb) @ attend), padded to [16][512] bf16 ----------------
__global__ __launch_bounds__(256) void k_amat(const int* __restrict__ classes,
                                              const float* __restrict__ ecw,
                                              const float* __restrict__ attend,
                                              unsigned short* __restrict__ a_bf) {
  __shared__ float tc[6][512];
  const int tid = threadIdx.x, j = blockIdx.x;   // j: h block [64j, 64j+64)
  for (int i = tid; i < 6 * 512; i += 256) {
    int c = i >> 9, hp = i & 511;
    tc[c][hp] = fast_tanh(ecw[(size_t)classes[c] * 512 + hp]);
  }
  __syncthreads();
  #pragma unroll
  for (int i = 0; i < 4; ++i) {
    int task = tid + 256 * i;          // 1024 tasks: c=task>>6 (0..15), hl=task&63
    int c = task >> 6, hl = task & 63;
    int h = j * 64 + hl;
    float v = 0.f;
    if (c < 6) {
      float acc = 0.f;
      for (int hp = 0; hp < 512; ++hp) acc += tc[c][hp] * attend[(size_t)hp * 512 + h];
      v = fast_tanh(acc);
    }
    a_bf[c * 512 + h] = f2bf(v);
  }
}

// ---------------- GRU recurrence: weight-stationary, SELF-VALIDATING TAGGED h ----------------
// grid 256 = 16 batch-groups (16 rows each) x 16 col-groups (32 hidden cols each)
// 384 threads = 6 waves; wave w owns 16 gate cols (g=w>>1 in {r,z,n}, half=(w&1))
// R9 protocol: h stored as u32 = [tag16|bf16]. A dword store is atomic -> tag and
// value land together; NO drain, NO flags, NO ordering assumptions. Consumers
// stage speculatively and re-load only stale dwords until all tags == s (staging
// IS the detection). Buffer-reuse invariant: tag s+2 in buf[s&1] can only appear
// after every block finished staging step s (producer progress implies it).
__global__ __launch_bounds__(384) void k_gru(
    const int* __restrict__ seq, const float* __restrict__ embed_W,
    const float* __restrict__ W_ih, const float* __restrict__ W_hh,
    const float* __restrict__ b_ih, const float* __restrict__ b_hh,
    unsigned* __restrict__ h_w, unsigned short* __restrict__ seq_repr,
    const unsigned short* __restrict__ x_pre, int xpre)
{
  __shared__ unsigned short x_lds[2][16][328];   // tanh(emb) bf16, K 300->320 (+8 pad)
  __shared__ unsigned short h_lds[16][520];      // h bf16 for MFMA A-frags
  __shared__ float rz_lds[2][16][32];            // r/z pre-activations

  const int tid = threadIdx.x;
  const int w = tid >> 6, l = tid & 63, lo = l & 15, hi = l >> 4;
  const int bid = blockIdx.x;
  const int g_b = (bid & 7) * 2 + (bid >> 7);    // batch group, XCD-clustered
  const int g_c = (bid >> 3) & 15;               // col group

  const int gg = w >> 1;                  // 0=r,1=z,2=n
  const int cb = (w & 1) * 16;
  const int jrow = gg * 512 + g_c * 32 + cb + lo;   // global gate row [0,1536)

  // --- weight fragments (persistent in VGPRs) ---
  s16x8 whh[16];
  #pragma unroll
  for (int kt = 0; kt < 16; ++kt) {
    const float* p = W_hh + (size_t)jrow * 512 + kt * 32 + hi * 8;
    f32x4 a0 = *(const f32x4*)p;
    f32x4 a1 = *(const f32x4*)(p + 4);
    s16x8 v;
    v[0]=(short)f2bf(a0[0]); v[1]=(short)f2bf(a0[1]); v[2]=(short)f2bf(a0[2]); v[3]=(short)f2bf(a0[3]);
    v[4]=(short)f2bf(a1[0]); v[5]=(short)f2bf(a1[1]); v[6]=(short)f2bf(a1[2]); v[7]=(short)f2bf(a1[3]);
    whh[kt] = v;
  }
  s16x8 wih[10];
  #pragma unroll
  for (int kt = 0; kt < 10; ++kt) {
    s16x8 v;
    #pragma unroll
    for (int jj = 0; jj < 8; ++jj) {
      int k = kt * 32 + hi * 8 + jj;
      float f = (k < NE) ? W_ih[(size_t)jrow * NE + k] : 0.f;
      v[jj] = (short)f2bf(f);
    }
    wih[kt] = v;
  }
  const float bsum = b_ih[jrow] + b_hh[jrow];
  const float bni = b_ih[jrow], bnh = b_hh[jrow];

  float hcar[4] = {0.f, 0.f, 0.f, 0.f};   // f32 carry, lane-owned

  // x-prefetch task indices for waves 1-5 (xpre path)
  const int xt = tid - 64;                 // 0..319 for w>=1
  const int xr0 = (xt >= 0) ? (xt / 40) : 0,          xc0 = (xt >= 0) ? (xt % 40) : 0;
  const int xr1 = (xt >= 0) ? ((xt + 320) / 40) : 0,  xc1 = (xt >= 0) ? ((xt + 320) % 40) : 0;

  auto do_gather = [&](int ss) {          // fallback: tanh(embed[seq[:,ss]]) -> x_lds[ss&1]
    const int buf = ss & 1;
    #pragma unroll
    for (int i = 0; i < 2; ++i) {
      int task = tid + 384 * i;
      if (task < 640) {
        int r = task & 15, grp = task >> 4;
        float vals[8];
        if (grp < 38) {
          int id = seq[(size_t)(g_b * 16 + r) * NS + ss];
          const float* ep = embed_W + (size_t)id * NE;
          if (grp < 37) {
            f32x4 u0 = *(const f32x4*)(ep + grp * 8);
            f32x4 u1 = *(const f32x4*)(ep + grp * 8 + 4);
            vals[0]=u0[0];vals[1]=u0[1];vals[2]=u0[2];vals[3]=u0[3];
            vals[4]=u1[0];vals[5]=u1[1];vals[6]=u1[2];vals[7]=u1[3];
          } else {
            #pragma unroll
            for (int jj = 0; jj < 8; ++jj) { int cc = 296 + jj; vals[jj] = (cc < NE) ? ep[cc] : 0.f; }
          }
        } else {
          #pragma unroll
          for (int jj = 0; jj < 8; ++jj) vals[jj] = 0.f;
        }
        s16x8 pv;
        #pragma unroll
        for (int jj = 0; jj < 8; ++jj) pv[jj] = (short)f2bf(fast_tanh(vals[jj]));
        *(s16x8*)&x_lds[buf][r][grp * 8] = pv;
      }
    }
  };

  if (xpre) {                             // prologue: synchronous fill of x_lds[0]
    if (w >= 1) {
      const unsigned short* src = x_pre + ((size_t)g_b * NS + 0) * (16 * 320);
      s16x8 v0 = *(const s16x8*)(src + xr0 * 320 + xc0 * 8);
      s16x8 v1 = *(const s16x8*)(src + xr1 * 320 + xc1 * 8);
      *(s16x8*)&x_lds[0][xr0][xc0 * 8] = v0;
      *(s16x8*)&x_lds[0][xr1][xc1 * 8] = v1;
    }
  } else {
    do_gather(0);
  }
  __syncthreads();                        // x_lds[0] ready for iter-0 ax

  #pragma unroll 1
  for (int s = 0; s < NS; ++s) {
    // ---- x-prefetch ISSUE (registers only; LDS write deferred past B2) ----
    const bool xpf = xpre && (s + 1 < NS) && (w >= 1);
    s16x8 xv0, xv1;
    if (xpf) {
      const unsigned short* src = x_pre + ((size_t)g_b * NS + (s + 1)) * (16 * 320);
      xv0 = *(const s16x8*)(src + xr0 * 320 + xc0 * 8);
      xv1 = *(const s16x8*)(src + xr1 * 320 + xc1 * 8);
    } else if (!xpre && s + 1 < NS) {
      do_gather(s + 1);
    }

    // ---- ax: h-independent GEMM, off the critical path ----
    f32x4 ax = {0.f,0.f,0.f,0.f};
    #pragma unroll
    for (int kt = 0; kt < 10; ++kt) {
      s16x8 af = *(const s16x8*)&x_lds[s & 1][lo][kt * 32 + hi * 8];
      ax = __builtin_amdgcn_mfma_f32_16x16x32_bf16(af, wih[kt], ax, 0, 0, 0);
    }

    // ---- speculative tagged stage: load h(s) image, retry stale dwords ----
    // buf[s&1] as u64[4096]; u64 = [tag|v(2c+1) | tag|v(2c)], expected tag = s.
    {
      const unsigned long long* hw =
          (const unsigned long long*)(h_w + ((size_t)(s & 1) * 16 + g_b) * (16 * 512));
      const unsigned tagp = (unsigned)s & 0xFFFFu;
      unsigned long long hv[11];
      unsigned need = 0;
      #pragma unroll
      for (int i = 0; i < 11; ++i) {
        int task = tid + 384 * i;
        if (task < 4096) {
          hv[i] = __hip_atomic_load(hw + task, __ATOMIC_RELAXED, __HIP_MEMORY_SCOPE_AGENT);
          need |= 1u << i;
        }
      }
      int guard = 0;
      for (;;) {
        unsigned bad = 0;
        #pragma unroll
        for (int i = 0; i < 11; ++i) if (need & (1u << i)) {
          unsigned t0 = (unsigned)(hv[i] >> 16) & 0xFFFFu;
          unsigned t1 = (unsigned)(hv[i] >> 48);
          if (t0 != tagp || t1 != tagp) bad |= 1u << i;
        }
        if (!bad) break;
        #pragma unroll
        for (int i = 0; i < 11; ++i) if (bad & (1u << i))
          hv[i] = __hip_atomic_load(hw + tid + 384 * i, __ATOMIC_RELAXED, __HIP_MEMORY_SCOPE_AGENT);
        need = bad;
        if (++guard > (1 << 13)) break;   // mechanism is per-dword atomic; never expected
      }
      #pragma unroll
      for (int i = 0; i < 11; ++i) {
        int task = tid + 384 * i;
        if (task < 4096) {
          int r = task >> 8, c2 = task & 255;     // 256 u64 per row
          unsigned packed = ((unsigned)(hv[i] & 0xFFFFu)) |
                            (((unsigned)(hv[i] >> 32) & 0xFFFFu) << 16);
          *(unsigned*)&h_lds[r][c2 * 2] = packed;
        }
      }
    }
    __syncthreads();                      // B2: h_lds ready

    // ---- deferred x-prefetch LDS write ----
    if (xpf) {
      *(s16x8*)&x_lds[(s + 1) & 1][xr0][xc0 * 8] = xv0;
      *(s16x8*)&x_lds[(s + 1) & 1][xr1][xc1 * 8] = xv1;
    }

    // ---- ah: 2 accumulator chains ----
    f32x4 ah0 = {0.f,0.f,0.f,0.f}, ah1 = {0.f,0.f,0.f,0.f};
    #pragma unroll
    for (int kt = 0; kt < 16; kt += 2) {
      s16x8 af0 = *(const s16x8*)&h_lds[lo][kt * 32 + hi * 8];
      s16x8 af1 = *(const s16x8*)&h_lds[lo][(kt + 1) * 32 + hi * 8];
      ah0 = __builtin_amdgcn_mfma_f32_16x16x32_bf16(af0, whh[kt], ah0, 0, 0, 0);
      ah1 = __builtin_amdgcn_mfma_f32_16x16x32_bf16(af1, whh[kt + 1], ah1, 0, 0, 0);
    }
    f32x4 ah = ah0 + ah1;

    if (w < 4) {                          // r,z: write pre-activations
      #pragma unroll
      for (int j = 0; j < 4; ++j) {
        int row = hi * 4 + j;
        rz_lds[gg][row][cb + lo] = ax[j] + ah[j] + bsum;
      }
    }
    __syncthreads();                      // B3

    if (w >= 4) {                         // n-gate waves: gates + tagged stores
      unsigned* hdst = h_w + ((size_t)((s + 1) & 1) * 16 + g_b) * (16 * 512);
      const int cpr = cb + lo;
      const int col = g_c * 32 + cpr;
      const unsigned tagn = ((unsigned)(s + 1) & 0xFFFFu) << 16;
      unsigned mybs[4];
      #pragma unroll
      for (int j = 0; j < 4; ++j) {
        int row = hi * 4 + j;
        float rr = sigm(rz_lds[0][row][cpr]);
        float zz = sigm(rz_lds[1][row][cpr]);
        float nn = fast_tanh(ax[j] + bni + rr * (ah[j] + bnh));
        float hn = (1.f - zz) * nn + zz * hcar[j];
        hcar[j] = hn;
        unsigned myb = (unsigned)f2bf(hn);
        mybs[j] = myb;
        // tagged h store: dword-atomic [tag|value] -> no ordering needed
        __hip_atomic_store(hdst + row * 512 + col, tagn | myb,
                           __ATOMIC_RELAXED, __HIP_MEMORY_SCOPE_AGENT);
      }
      // seq_repr (bf16 pairs, off-path)
      #pragma unroll
      for (int j = 0; j < 4; ++j) {
        unsigned other = __shfl_xor(mybs[j], 1);
        if ((lo & 1) == 0) {
          unsigned word = mybs[j] | (other << 16);
          *(unsigned*)(seq_repr + ((size_t)(g_b * 16 + hi * 4 + j) * NS + s) * NH + col) = word;
        }
      }
    }
    // no drain, no flag, no trailing barrier
  }
}

// ---------------- attention + logits + log_softmax, one WG per batch row ----------------
__global__ __launch_bounds__(256) void k_attn(const int* __restrict__ seq,
                                              const unsigned short* __restrict__ seq_repr,
                                              const unsigned short* __restrict__ a_bf,
                                              const float* __restrict__ W_cls,
                                              const float* __restrict__ b_cls,
                                              float* __restrict__ out)
{
  __shared__ unsigned short V[32][520];
  __shared__ float P[32][8];
  __shared__ float red[4][12];
  const int tid = threadIdx.x, b = blockIdx.x;
  const int w = tid >> 6, l = tid & 63, lo = l & 15, hi = l >> 4;

  s16x8 afr[16];                          // B-frags of a (class attn vectors)
  #pragma unroll
  for (int kt = 0; kt < 16; ++kt)
    afr[kt] = *(const s16x8*)(a_bf + (size_t)lo * 512 + kt * 32 + hi * 8);

  float ctx0[6] = {0,0,0,0,0,0}, ctx1[6] = {0,0,0,0,0,0};   // h = 2*tid, 2*tid+1
  const unsigned short* vbase = seq_repr + (size_t)b * NS * NH;

  for (int sc = 0; sc < 16; ++sc) {
    #pragma unroll 4
    for (int i = 0; i < 8; ++i) {         // stage 32 x 512 bf16
      int task = tid + 256 * i;
      int sl = task >> 6, grp = task & 63;
      s16x8 v = *(const s16x8*)(vbase + (size_t)(sc * 32 + sl) * NH + grp * 8);
      *(s16x8*)&V[sl][grp * 8] = v;
    }
    __syncthreads();
    if (w < 2) {                          // scores via MFMA: [16 s][6 c]
      f32x4 acc = {0.f,0.f,0.f,0.f};
      int sl0 = w * 16;
      #pragma unroll
      for (int kt = 0; kt < 16; ++kt) {
        s16x8 af = *(const s16x8*)&V[sl0 + lo][kt * 32 + hi * 8];
        acc = __builtin_amdgcn_mfma_f32_16x16x32_bf16(af, afr[kt], acc, 0, 0, 0);
      }
      if (lo < 8) {
        #pragma unroll
        for (int j = 0; j < 4; ++j) {
          int sl = sl0 + hi * 4 + j;
          float p = 0.f;
          if (lo < 6) {
            int s = sc * 32 + sl;
            p = (seq[(size_t)b * NS + s] > 0) ? fast_tanh(acc[j]) : 0.f;
          }
          P[sl][lo] = p;
        }
      }
    }
    __syncthreads();
    #pragma unroll 2
    for (int sl = 0; sl < 32; ++sl) {     // ctx += tanh(score) * V
      unsigned v2 = *(const unsigned*)&V[sl][tid * 2];
      float v0 = bf2f((unsigned short)(v2 & 0xFFFFu));
      float v1 = bf2f((unsigned short)(v2 >> 16));
      #pragma unroll
      for (int c = 0; c < 6; ++c) {
        float p = P[sl][c];
        ctx0[c] += p * v0; ctx1[c] += p * v1;
      }
    }
    __syncthreads();
  }

  // logits + log_softmax
  float pl[12];
  #pragma unroll
  for (int c = 0; c < 6; ++c) {
    float t0 = fast_tanh(ctx0[c]), t1 = fast_tanh(ctx1[c]);
    pl[c * 2 + 0] = t0 * W_cls[tid * 2] + t1 * W_cls[tid * 2 + 1];
    pl[c * 2 + 1] = t0 * W_cls[512 + tid * 2] + t1 * W_cls[512 + tid * 2 + 1];
  }
  #pragma unroll
  for (int i = 0; i < 12; ++i) {
    float v = pl[i];
    for (int off = 32; off > 0; off >>= 1) v += __shfl_down(v, off);
    if (l == 0) red[w][i] = v;
  }
  __syncthreads();
  if (tid < 6) {
    int c = tid;
    float l0 = red[0][c*2] + red[1][c*2] + red[2][c*2] + red[3][c*2] + b_cls[0];
    float l1 = red[0][c*2+1] + red[1][c*2+1] + red[2][c*2+1] + red[3][c*2+1] + b_cls[1];
    float m = fmaxf(l0, l1);
    float lse = m + logf(__expf(l0 - m) + __expf(l1 - m));
    out[c * 512 + b * 2 + 0] = l0 - lse;
    out[c * 512 + b * 2 + 1] = l1 - lse;
  }
}

extern "C" void kernel_launch(void* const* d_in, const int* in_sizes, int n_in,
                              void* d_out, int out_size, void* d_ws, size_t ws_size,
                              hipStream_t stream) {
  const int*   seq      = (const int*)d_in[0];
  const int*   classes  = (const int*)d_in[1];
  const float* embed_W  = (const float*)d_in[2];
  const float* ecw      = (const float*)d_in[3];
  const float* W_ih     = (const float*)d_in[4];
  const float* W_hh     = (const float*)d_in[5];
  const float* b_ih     = (const float*)d_in[6];
  const float* b_hh     = (const float*)d_in[7];
  const float* attend   = (const float*)d_in[8];
  const float* W_cls    = (const float*)d_in[9];
  const float* b_cls    = (const float*)d_in[10];
  float* out = (float*)d_out;

  char* ws = (char*)d_ws;
  const size_t OFF_HW   = 134217728;                 // after seq_repr (128MB)
  const size_t OFF_ABF  = OFF_HW + 1048576;          // tagged h: 2*16*16*512*4B = 1MB
  const size_t OFF_XPRE = OFF_ABF + 16384;
  const size_t XPRE_BYTES = (size_t)16 * NS * 16 * 320 * 2;   // 83,886,080
  unsigned short* seq_repr = (unsigned short*)ws;
  unsigned*       h_w      = (unsigned*)(ws + OFF_HW);
  unsigned short* a_bf     = (unsigned short*)(ws + OFF_ABF);
  unsigned short* x_pre    = (unsigned short*)(ws + OFF_XPRE);
  const int xpre = (ws_size >= OFF_XPRE + XPRE_BYTES) ? 1 : 0;

  hipLaunchKernelGGL(k_zero, dim3(64), dim3(256), 0, stream, h_w);
  hipLaunchKernelGGL(k_amat, dim3(8), dim3(256), 0, stream, classes, ecw, attend, a_bf);
  if (xpre)
    hipLaunchKernelGGL(k_xemb, dim3(2048), dim3(256), 0, stream, seq, embed_W, x_pre);
  hipLaunchKernelGGL(k_gru, dim3(256), dim3(384), 0, stream,
                     seq, embed_W, W_ih, W_hh, b_ih, b_hh, h_w, seq_repr,
                     x_pre, xpre);
  hipLaunchKernelGGL(k_attn, dim3(256), dim3(256), 0, stream,
                     seq, seq_repr, a_bf, W_cls, b_cls, out);
}

// Round 10
// 2152.479 us; speedup vs baseline: 1.2662x; 1.2662x over previous
//
#include <hip/hip_runtime.h>
#include <cstdint>
#include <cstddef>

#define NB 256
#define NS 512
#define NE 300
#define NH 512

using f32x4 = __attribute__((ext_vector_type(4))) float;
using s16x8 = __attribute__((ext_vector_type(8))) short;

static __device__ __forceinline__ unsigned short f2bf(float f) {
  unsigned u = __float_as_uint(f);
  u += 0x7FFFu + ((u >> 16) & 1u);
  return (unsigned short)(u >> 16);
}
static __device__ __forceinline__ float bf2f(unsigned short h) {
  return __uint_as_float(((unsigned)h) << 16);
}
static __device__ __forceinline__ float fast_tanh(float x) {
  float xc = fminf(fmaxf(x, -9.f), 9.f);
  float e = __expf(2.f * xc);
  return (e - 1.f) / (e + 1.f);
}
static __device__ __forceinline__ float sigm(float x) {
  return 1.f / (1.f + __expf(-x));
}

// ---------------- init: agent-scope zero of h_ex + flags ----------------
__global__ void k_zero(unsigned short* __restrict__ h_ex, unsigned* __restrict__ flags) {
  int i = blockIdx.x * 256 + threadIdx.x;   // grid 64 -> 16384 threads
  unsigned long long* p = (unsigned long long*)(h_ex + (size_t)i * 16);
  #pragma unroll
  for (int j = 0; j < 4; ++j)
    __hip_atomic_store(p + j, 0ull, __ATOMIC_RELAXED, __HIP_MEMORY_SCOPE_AGENT);
  if (i < 4096)
    __hip_atomic_store(flags + i, 0u, __ATOMIC_RELAXED, __HIP_MEMORY_SCOPE_AGENT);
}

// ---------------- x_pre = tanh(embed_W[seq]) as bf16, layout [g_b][s][16][320] ----------------
__global__ __launch_bounds__(256) void k_xemb(const int* __restrict__ seq,
                                              const float* __restrict__ embed_W,
                                              unsigned short* __restrict__ x_pre) {
  const long long total = (long long)NB * NS * 40;   // tasks of 8 cols
  for (long long t = (long long)blockIdx.x * 256 + threadIdx.x; t < total;
       t += (long long)gridDim.x * 256) {
    int c = (int)(t % 40);
    long long p = t / 40;
    int s = (int)(p % NS);
    int b = (int)(p / NS);
    int g_b = b >> 4, r = b & 15;
    float vals[8];
    if (c < 38) {
      int id = seq[(size_t)b * NS + s];
      const float* ep = embed_W + (size_t)id * NE;
      if (c < 37) {
        f32x4 u0 = *(const f32x4*)(ep + c * 8);
        f32x4 u1 = *(const f32x4*)(ep + c * 8 + 4);
        vals[0]=u0[0];vals[1]=u0[1];vals[2]=u0[2];vals[3]=u0[3];
        vals[4]=u1[0];vals[5]=u1[1];vals[6]=u1[2];vals[7]=u1[3];
      } else {
        #pragma unroll
        for (int jj = 0; jj < 8; ++jj) { int cc = 296 + jj; vals[jj] = (cc < NE) ? ep[cc] : 0.f; }
      }
    } else {
      #pragma unroll
      for (int jj = 0; jj < 8; ++jj) vals[jj] = 0.f;
    }
    s16x8 pv;
    #pragma unroll
    for (int jj = 0; jj < 8; ++jj) pv[jj] = (short)f2bf(fast_tanh(vals[jj]));
    *(s16x8*)(x_pre + (((size_t)g_b * NS + s) * 16 + r) * 320 + c * 8) = pv;
  }
}

// ---------------- a = tanh(tanh(class_emb) @ attend), padded to [16][512] bf16 ----------------
__global__ __launch_bounds__(256) void k_amat(const int* __restrict__ classes,
                                              const float* __restrict__ ecw,
                                              const float* __restrict__ attend,
                                              unsigned short* __restrict__ a_bf) {
  __shared__ float tc[6][512];
  const int tid = threadIdx.x, j = blockIdx.x;   // j: h block [64j, 64j+64)
  for (int i = tid; i < 6 * 512; i += 256) {
    int c = i >> 9, hp = i & 511;
    tc[c][hp] = fast_tanh(ecw[(size_t)classes[c] * 512 + hp]);
  }
  __syncthreads();
  #pragma unroll
  for (int i = 0; i < 4; ++i) {
    int task = tid + 256 * i;          // 1024 tasks: c=task>>6 (0..15), hl=task&63
    int c = task >> 6, hl = task & 63;
    int h = j * 64 + hl;
    float v = 0.f;
    if (c < 6) {
      float acc = 0.f;
      for (int hp = 0; hp < 512; ++hp) acc += tc[c][hp] * attend[(size_t)hp * 512 + h];
      v = fast_tanh(acc);
    }
    a_bf[c * 512 + h] = f2bf(v);
  }
}

// ---------------- GRU recurrence: weight-stationary, agent flags, DEDICATED SYNC WAVE ----------------
// grid 256 = 16 batch-groups x 16 col-groups; 448 threads = 7 waves.
// Waves 0-5: compute (w>>1 = gate, w&1 = col half), wave 6: pure detector —
// no weights/MFMA/x-loads, sits in a tight no-sleep poll so detection overlaps
// the producers' gate+store phase instead of trailing wave-0's compute (R7/R8
// had wave 0 do x-issue + 10 MFMAs before polling).
__global__ __launch_bounds__(448) void k_gru(
    const int* __restrict__ seq, const float* __restrict__ embed_W,
    const float* __restrict__ W_ih, const float* __restrict__ W_hh,
    const float* __restrict__ b_ih, const float* __restrict__ b_hh,
    unsigned short* __restrict__ h_ex, unsigned* __restrict__ flags,
    unsigned short* __restrict__ seq_repr,
    const unsigned short* __restrict__ x_pre, int xpre)
{
  __shared__ unsigned short x_lds[2][16][328];   // tanh(emb) bf16, K 300->320 (+8 pad)
  __shared__ unsigned short h_lds[16][520];      // h bf16 for MFMA A-frags
  __shared__ float rz_lds[2][16][32];            // r/z pre-activations

  const int tid = threadIdx.x;
  const int w = tid >> 6, l = tid & 63, lo = l & 15, hi = l >> 4;
  const bool cw = (w < 6);                // compute wave?
  const int bid = blockIdx.x;
  const int g_b = (bid & 7) * 2 + (bid >> 7);    // batch group, XCD-clustered
  const int g_c = (bid >> 3) & 15;               // col group

  const int gg = (w < 6) ? (w >> 1) : 0;  // 0=r,1=z,2=n
  const int cb = (w & 1) * 16;
  const int jrow = cw ? (gg * 512 + g_c * 32 + cb + lo) : 0;  // gate row [0,1536)

  // --- weight fragments (persistent in VGPRs; waves 0-5 only) ---
  s16x8 whh[16];
  s16x8 wih[10];
  float bsum = 0.f, bni = 0.f, bnh = 0.f;
  if (cw) {
    #pragma unroll
    for (int kt = 0; kt < 16; ++kt) {
      const float* p = W_hh + (size_t)jrow * 512 + kt * 32 + hi * 8;
      f32x4 a0 = *(const f32x4*)p;
      f32x4 a1 = *(const f32x4*)(p + 4);
      s16x8 v;
      v[0]=(short)f2bf(a0[0]); v[1]=(short)f2bf(a0[1]); v[2]=(short)f2bf(a0[2]); v[3]=(short)f2bf(a0[3]);
      v[4]=(short)f2bf(a1[0]); v[5]=(short)f2bf(a1[1]); v[6]=(short)f2bf(a1[2]); v[7]=(short)f2bf(a1[3]);
      whh[kt] = v;
    }
    #pragma unroll
    for (int kt = 0; kt < 10; ++kt) {
      s16x8 v;
      #pragma unroll
      for (int jj = 0; jj < 8; ++jj) {
        int k = kt * 32 + hi * 8 + jj;
        float f = (k < NE) ? W_ih[(size_t)jrow * NE + k] : 0.f;
        v[jj] = (short)f2bf(f);
      }
      wih[kt] = v;
    }
    bsum = b_ih[jrow] + b_hh[jrow];
    bni = b_ih[jrow]; bnh = b_hh[jrow];
  }

  float hcar[4] = {0.f, 0.f, 0.f, 0.f};   // f32 carry, lane-owned
  const unsigned* flg = flags + g_b * 32;  // 32 half-flags for my batch group

  // x-prefetch task indices for waves 1-5 (xpre path)
  const int xt = tid - 64;                 // 0..319 for waves 1-5
  const bool xw = (w >= 1 && w < 6);
  const int xr0 = xw ? (xt / 40) : 0,          xc0 = xw ? (xt % 40) : 0;
  const int xr1 = xw ? ((xt + 320) / 40) : 0,  xc1 = xw ? ((xt + 320) % 40) : 0;

  auto do_gather = [&](int ss) {          // fallback: tanh(embed[seq[:,ss]]) -> x_lds[ss&1]
    const int buf = ss & 1;
    #pragma unroll
    for (int i = 0; i < 2; ++i) {
      int task = tid + 448 * i;
      if (task < 640) {
        int r = task & 15, grp = task >> 4;
        float vals[8];
        if (grp < 38) {
          int id = seq[(size_t)(g_b * 16 + r) * NS + ss];
          const float* ep = embed_W + (size_t)id * NE;
          if (grp < 37) {
            f32x4 u0 = *(const f32x4*)(ep + grp * 8);
            f32x4 u1 = *(const f32x4*)(ep + grp * 8 + 4);
            vals[0]=u0[0];vals[1]=u0[1];vals[2]=u0[2];vals[3]=u0[3];
            vals[4]=u1[0];vals[5]=u1[1];vals[6]=u1[2];vals[7]=u1[3];
          } else {
            #pragma unroll
            for (int jj = 0; jj < 8; ++jj) { int cc = 296 + jj; vals[jj] = (cc < NE) ? ep[cc] : 0.f; }
          }
        } else {
          #pragma unroll
          for (int jj = 0; jj < 8; ++jj) vals[jj] = 0.f;
        }
        s16x8 pv;
        #pragma unroll
        for (int jj = 0; jj < 8; ++jj) pv[jj] = (short)f2bf(fast_tanh(vals[jj]));
        *(s16x8*)&x_lds[buf][r][grp * 8] = pv;
      }
    }
  };

  if (xpre) {                             // prologue: synchronous fill of x_lds[0]
    if (xw) {
      const unsigned short* src = x_pre + ((size_t)g_b * NS + 0) * (16 * 320);
      s16x8 v0 = *(const s16x8*)(src + xr0 * 320 + xc0 * 8);
      s16x8 v1 = *(const s16x8*)(src + xr1 * 320 + xc1 * 8);
      *(s16x8*)&x_lds[0][xr0][xc0 * 8] = v0;
      *(s16x8*)&x_lds[0][xr1][xc1 * 8] = v1;
    }
  } else {
    do_gather(0);
  }
  __syncthreads();                        // x_lds[0] ready for iter-0 ax

  #pragma unroll 1
  for (int s = 0; s < NS; ++s) {
    // ---- wave 6: dedicated tight poll (no sleep, 1 coalesced load / RT) ----
    if (!cw) {
      if (s > 0) {
        const unsigned* fp = flg + (l & 31);
        int guard = 0;
        for (;;) {
          unsigned f = __hip_atomic_load(fp, __ATOMIC_RELAXED, __HIP_MEMORY_SCOPE_AGENT);
          if (__all(f >= (unsigned)s)) break;
          if (++guard > (1 << 22)) break;   // safety: never hang
        }
      }
    } else {
      // ---- compute waves: x-prefetch issue + ax while wave 6 detects ----
      const bool xpf = xpre && (s + 1 < NS) && xw;
      s16x8 xv0, xv1;
      if (xpf) {
        const unsigned short* src = x_pre + ((size_t)g_b * NS + (s + 1)) * (16 * 320);
        xv0 = *(const s16x8*)(src + xr0 * 320 + xc0 * 8);
        xv1 = *(const s16x8*)(src + xr1 * 320 + xc1 * 8);
        // write deferred to post-B2 via registers below (lambda-free: fallthrough)
        // stash in LDS after B2 — handled after staging (see below)
      } else if (!xpre && s + 1 < NS) {
        do_gather(s + 1);
      }
      // ax: h-independent GEMM
      f32x4 ax_ = {0.f,0.f,0.f,0.f};
      #pragma unroll
      for (int kt = 0; kt < 10; ++kt) {
        s16x8 af = *(const s16x8*)&x_lds[s & 1][lo][kt * 32 + hi * 8];
        ax_ = __builtin_amdgcn_mfma_f32_16x16x32_bf16(af, wih[kt], ax_, 0, 0, 0);
      }
      // persist ax_ and xv in registers across the barrier (no LDS)
      // fall through to shared code below with locals:
      __syncthreads();                    // B1: wave 6 confirmed h(s) ready

      // ---- stage h (all 7 waves; this branch covers waves 0-5) ----
      const unsigned short* hsrc = h_ex + ((size_t)(s & 1) * 16 + g_b) * (16 * 512);
      #pragma unroll
      for (int i = 0; i < 5; ++i) {
        int task = tid + 448 * i;
        if (task < 2048) {
          int r = task >> 7, c4 = task & 127;
          unsigned long long v = __hip_atomic_load(
              (const unsigned long long*)(hsrc + r * 512 + c4 * 4),
              __ATOMIC_RELAXED, __HIP_MEMORY_SCOPE_AGENT);
          *(unsigned long long*)&h_lds[r][c4 * 4] = v;
        }
      }
      __syncthreads();                    // B2

      // deferred x-prefetch LDS write
      if (xpf) {
        *(s16x8*)&x_lds[(s + 1) & 1][xr0][xc0 * 8] = xv0;
        *(s16x8*)&x_lds[(s + 1) & 1][xr1][xc1 * 8] = xv1;
      }

      // ah: 2 accumulator chains
      f32x4 ah0 = {0.f,0.f,0.f,0.f}, ah1 = {0.f,0.f,0.f,0.f};
      #pragma unroll
      for (int kt = 0; kt < 16; kt += 2) {
        s16x8 af0 = *(const s16x8*)&h_lds[lo][kt * 32 + hi * 8];
        s16x8 af1 = *(const s16x8*)&h_lds[lo][(kt + 1) * 32 + hi * 8];
        ah0 = __builtin_amdgcn_mfma_f32_16x16x32_bf16(af0, whh[kt], ah0, 0, 0, 0);
        ah1 = __builtin_amdgcn_mfma_f32_16x16x32_bf16(af1, whh[kt + 1], ah1, 0, 0, 0);
      }
      f32x4 ah = ah0 + ah1;

      if (w < 4) {                        // r,z: write pre-activations
        #pragma unroll
        for (int j = 0; j < 4; ++j) {
          int row = hi * 4 + j;
          rz_lds[gg][row][cb + lo] = ax_[j] + ah[j] + bsum;
        }
      }
      __syncthreads();                    // B3

      if (w >= 4) {                       // n-gate waves combine + update + signal
        unsigned short* hdst = h_ex + ((size_t)((s + 1) & 1) * 16 + g_b) * (16 * 512);
        const int cpr = cb + lo;
        const int col = g_c * 32 + cpr;
        unsigned words[4];
        #pragma unroll
        for (int j = 0; j < 4; ++j) {
          int row = hi * 4 + j;
          float rr = sigm(rz_lds[0][row][cpr]);
          float zz = sigm(rz_lds[1][row][cpr]);
          float nn = fast_tanh(ax_[j] + bni + rr * (ah[j] + bnh));
          float hn = (1.f - zz) * nn + zz * hcar[j];
          hcar[j] = hn;
          unsigned myb = (unsigned)f2bf(hn);
          unsigned other = __shfl_xor(myb, 1);
          words[j] = myb | (other << 16);
        }
        if ((lo & 1) == 0) {              // even lane stores the packed pair
          #pragma unroll
          for (int j = 0; j < 4; ++j)
            __hip_atomic_store((unsigned*)(hdst + (hi * 4 + j) * 512 + col), words[j],
                               __ATOMIC_RELAXED, __HIP_MEMORY_SCOPE_AGENT);
        }
        asm volatile("s_waitcnt vmcnt(0)" ::: "memory");  // drain h stores
        if (l == 0)                       // signal: this n-wave's half done
          __hip_atomic_store((unsigned*)(flags + g_b * 32 + g_c * 2 + (w & 1)),
                             (unsigned)(s + 1),
                             __ATOMIC_RELAXED, __HIP_MEMORY_SCOPE_AGENT);
        if ((lo & 1) == 0) {              // seq_repr writes: in-flight, off-path
          #pragma unroll
          for (int j = 0; j < 4; ++j)
            *(unsigned*)(seq_repr + ((size_t)(g_b * 16 + hi * 4 + j) * NS + s) * NH + col) = words[j];
        }
      }
      continue;                           // compute-wave path done for this s
    }

    // ---- wave 6 joins the barriers + staging ----
    __syncthreads();                      // B1
    {
      const unsigned short* hsrc = h_ex + ((size_t)(s & 1) * 16 + g_b) * (16 * 512);
      #pragma unroll
      for (int i = 0; i < 5; ++i) {
        int task = tid + 448 * i;
        if (task < 2048) {
          int r = task >> 7, c4 = task & 127;
          unsigned long long v = __hip_atomic_load(
              (const unsigned long long*)(hsrc + r * 512 + c4 * 4),
              __ATOMIC_RELAXED, __HIP_MEMORY_SCOPE_AGENT);
          *(unsigned long long*)&h_lds[r][c4 * 4] = v;
        }
      }
    }
    __syncthreads();                      // B2
    __syncthreads();                      // B3
  }

// ---------------- attention epilogue unchanged ----------------
}

__global__ __launch_bounds__(256) void k_attn(const int* __restrict__ seq,
                                              const unsigned short* __restrict__ seq_repr,
                                              const unsigned short* __restrict__ a_bf,
                                              const float* __restrict__ W_cls,
                                              const float* __restrict__ b_cls,
                                              float* __restrict__ out)
{
  __shared__ unsigned short V[32][520];
  __shared__ float P[32][8];
  __shared__ float red[4][12];
  const int tid = threadIdx.x, b = blockIdx.x;
  const int w = tid >> 6, l = tid & 63, lo = l & 15, hi = l >> 4;

  s16x8 afr[16];                          // B-frags of a (class attn vectors)
  #pragma unroll
  for (int kt = 0; kt < 16; ++kt)
    afr[kt] = *(const s16x8*)(a_bf + (size_t)lo * 512 + kt * 32 + hi * 8);

  float ctx0[6] = {0,0,0,0,0,0}, ctx1[6] = {0,0,0,0,0,0};   // h = 2*tid, 2*tid+1
  const unsigned short* vbase = seq_repr + (size_t)b * NS * NH;

  for (int sc = 0; sc < 16; ++sc) {
    #pragma unroll 4
    for (int i = 0; i < 8; ++i) {         // stage 32 x 512 bf16
      int task = tid + 256 * i;
      int sl = task >> 6, grp = task & 63;
      s16x8 v = *(const s16x8*)(vbase + (size_t)(sc * 32 + sl) * NH + grp * 8);
      *(s16x8*)&V[sl][grp * 8] = v;
    }
    __syncthreads();
    if (w < 2) {                          // scores via MFMA: [16 s][6 c]
      f32x4 acc = {0.f,0.f,0.f,0.f};
      int sl0 = w * 16;
      #pragma unroll
      for (int kt = 0; kt < 16; ++kt) {
        s16x8 af = *(const s16x8*)&V[sl0 + lo][kt * 32 + hi * 8];
        acc = __builtin_amdgcn_mfma_f32_16x16x32_bf16(af, afr[kt], acc, 0, 0, 0);
      }
      if (lo < 8) {
        #pragma unroll
        for (int j = 0; j < 4; ++j) {
          int sl = sl0 + hi * 4 + j;
          float p = 0.f;
          if (lo < 6) {
            int s = sc * 32 + sl;
            p = (seq[(size_t)b * NS + s] > 0) ? fast_tanh(acc[j]) : 0.f;
          }
          P[sl][lo] = p;
        }
      }
    }
    __syncthreads();
    #pragma unroll 2
    for (int sl = 0; sl < 32; ++sl) {     // ctx += tanh(score) * V
      unsigned v2 = *(const unsigned*)&V[sl][tid * 2];
      float v0 = bf2f((unsigned short)(v2 & 0xFFFFu));
      float v1 = bf2f((unsigned short)(v2 >> 16));
      #pragma unroll
      for (int c = 0; c < 6; ++c) {
        float p = P[sl][c];
        ctx0[c] += p * v0; ctx1[c] += p * v1;
      }
    }
    __syncthreads();
  }

  // logits + log_softmax
  float pl[12];
  #pragma unroll
  for (int c = 0; c < 6; ++c) {
    float t0 = fast_tanh(ctx0[c]), t1 = fast_tanh(ctx1[c]);
    pl[c * 2 + 0] = t0 * W_cls[tid * 2] + t1 * W_cls[tid * 2 + 1];
    pl[c * 2 + 1] = t0 * W_cls[512 + tid * 2] + t1 * W_cls[512 + tid * 2 + 1];
  }
  #pragma unroll
  for (int i = 0; i < 12; ++i) {
    float v = pl[i];
    for (int off = 32; off > 0; off >>= 1) v += __shfl_down(v, off);
    if (l == 0) red[w][i] = v;
  }
  __syncthreads();
  if (tid < 6) {
    int c = tid;
    float l0 = red[0][c*2] + red[1][c*2] + red[2][c*2] + red[3][c*2] + b_cls[0];
    float l1 = red[0][c*2+1] + red[1][c*2+1] + red[2][c*2+1] + red[3][c*2+1] + b_cls[1];
    float m = fmaxf(l0, l1);
    float lse = m + logf(__expf(l0 - m) + __expf(l1 - m));
    out[c * 512 + b * 2 + 0] = l0 - lse;
    out[c * 512 + b * 2 + 1] = l1 - lse;
  }
}

extern "C" void kernel_launch(void* const* d_in, const int* in_sizes, int n_in,
                              void* d_out, int out_size, void* d_ws, size_t ws_size,
                              hipStream_t stream) {
  const int*   seq      = (const int*)d_in[0];
  const int*   classes  = (const int*)d_in[1];
  const float* embed_W  = (const float*)d_in[2];
  const float* ecw      = (const float*)d_in[3];
  const float* W_ih     = (const float*)d_in[4];
  const float* W_hh     = (const float*)d_in[5];
  const float* b_ih     = (const float*)d_in[6];
  const float* b_hh     = (const float*)d_in[7];
  const float* attend   = (const float*)d_in[8];
  const float* W_cls    = (const float*)d_in[9];
  const float* b_cls    = (const float*)d_in[10];
  float* out = (float*)d_out;

  char* ws = (char*)d_ws;
  const size_t OFF_HEX  = 134217728;                 // after seq_repr
  const size_t OFF_FLG  = OFF_HEX + 524288;
  const size_t OFF_ABF  = OFF_FLG + 16384;
  const size_t OFF_XPRE = OFF_ABF + 16384;
  const size_t XPRE_BYTES = (size_t)16 * NS * 16 * 320 * 2;   // 83,886,080
  unsigned short* seq_repr = (unsigned short*)ws;
  unsigned short* h_ex     = (unsigned short*)(ws + OFF_HEX);
  unsigned*       flags    = (unsigned*)(ws + OFF_FLG);
  unsigned short* a_bf     = (unsigned short*)(ws + OFF_ABF);
  unsigned short* x_pre    = (unsigned short*)(ws + OFF_XPRE);
  const int xpre = (ws_size >= OFF_XPRE + XPRE_BYTES) ? 1 : 0;

  hipLaunchKernelGGL(k_zero, dim3(64), dim3(256), 0, stream, h_ex, flags);
  hipLaunchKernelGGL(k_amat, dim3(8), dim3(256), 0, stream, classes, ecw, attend, a_bf);
  if (xpre)
    hipLaunchKernelGGL(k_xemb, dim3(2048), dim3(256), 0, stream, seq, embed_W, x_pre);
  hipLaunchKernelGGL(k_gru, dim3(256), dim3(448), 0, stream,
                     seq, embed_W, W_ih, W_hh, b_ih, b_hh, h_ex, flags, seq_repr,
                     x_pre, xpre);
  hipLaunchKernelGGL(k_attn, dim3(256), dim3(256), 0, stream,
                     seq, seq_repr, a_bf, W_cls, b_cls, out);
}

// Round 11
// 2047.105 us; speedup vs baseline: 1.3314x; 1.0515x over previous
//
#include <hip/hip_runtime.h>
#include <cstdint>
#include <cstddef>

#define NB 256
#define NS 512
#define NE 300
#define NH 512

using f32x4 = __attribute__((ext_vector_type(4))) float;
using s16x8 = __attribute__((ext_vector_type(8))) short;

static __device__ __forceinline__ unsigned short f2bf(float f) {
  unsigned u = __float_as_uint(f);
  u += 0x7FFFu + ((u >> 16) & 1u);
  return (unsigned short)(u >> 16);
}
static __device__ __forceinline__ float bf2f(unsigned short h) {
  return __uint_as_float(((unsigned)h) << 16);
}
static __device__ __forceinline__ float fast_tanh(float x) {
  float xc = fminf(fmaxf(x, -9.f), 9.f);
  float e = __expf(2.f * xc);
  return (e - 1.f) / (e + 1.f);
}
static __device__ __forceinline__ float sigm(float x) {
  return 1.f / (1.f + __expf(-x));
}

// ---------------- init: agent-scope zero of h_ex + flags ----------------
__global__ void k_zero(unsigned short* __restrict__ h_ex, unsigned* __restrict__ flags) {
  int i = blockIdx.x * 256 + threadIdx.x;   // grid 64 -> 16384 threads
  unsigned long long* p = (unsigned long long*)(h_ex + (size_t)i * 16);
  #pragma unroll
  for (int j = 0; j < 4; ++j)
    __hip_atomic_store(p + j, 0ull, __ATOMIC_RELAXED, __HIP_MEMORY_SCOPE_AGENT);
  if (i < 4096)
    __hip_atomic_store(flags + i, 0u, __ATOMIC_RELAXED, __HIP_MEMORY_SCOPE_AGENT);
}

// ---------------- x_pre = tanh(embed_W[seq]) as bf16, layout [g_b][s][16][320] ----------------
__global__ __launch_bounds__(256) void k_xemb(const int* __restrict__ seq,
                                              const float* __restrict__ embed_W,
                                              unsigned short* __restrict__ x_pre) {
  const long long total = (long long)NB * NS * 40;   // tasks of 8 cols
  for (long long t = (long long)blockIdx.x * 256 + threadIdx.x; t < total;
       t += (long long)gridDim.x * 256) {
    int c = (int)(t % 40);
    long long p = t / 40;
    int s = (int)(p % NS);
    int b = (int)(p / NS);
    int g_b = b >> 4, r = b & 15;
    float vals[8];
    if (c < 38) {
      int id = seq[(size_t)b * NS + s];
      const float* ep = embed_W + (size_t)id * NE;
      if (c < 37) {
        f32x4 u0 = *(const f32x4*)(ep + c * 8);
        f32x4 u1 = *(const f32x4*)(ep + c * 8 + 4);
        vals[0]=u0[0];vals[1]=u0[1];vals[2]=u0[2];vals[3]=u0[3];
        vals[4]=u1[0];vals[5]=u1[1];vals[6]=u1[2];vals[7]=u1[3];
      } else {
        #pragma unroll
        for (int jj = 0; jj < 8; ++jj) { int cc = 296 + jj; vals[jj] = (cc < NE) ? ep[cc] : 0.f; }
      }
    } else {
      #pragma unroll
      for (int jj = 0; jj < 8; ++jj) vals[jj] = 0.f;
    }
    s16x8 pv;
    #pragma unroll
    for (int jj = 0; jj < 8; ++jj) pv[jj] = (short)f2bf(fast_tanh(vals[jj]));
    *(s16x8*)(x_pre + (((size_t)g_b * NS + s) * 16 + r) * 320 + c * 8) = pv;
  }
}

// ---------------- a = tanh(tanh(class_emb) @ attend), padded to [16][512] bf16 ----------------
__global__ __launch_bounds__(256) void k_amat(const int* __restrict__ classes,
                                              const float* __restrict__ ecw,
                                              const float* __restrict__ attend,
                                              unsigned short* __restrict__ a_bf) {
  __shared__ float tc[6][512];
  const int tid = threadIdx.x, j = blockIdx.x;   // j: h block [64j, 64j+64)
  for (int i = tid; i < 6 * 512; i += 256) {
    int c = i >> 9, hp = i & 511;
    tc[c][hp] = fast_tanh(ecw[(size_t)classes[c] * 512 + hp]);
  }
  __syncthreads();
  #pragma unroll
  for (int i = 0; i < 4; ++i) {
    int task = tid + 256 * i;          // 1024 tasks: c=task>>6 (0..15), hl=task&63
    int c = task >> 6, hl = task & 63;
    int h = j * 64 + hl;
    float v = 0.f;
    if (c < 6) {
      float acc = 0.f;
      for (int hp = 0; hp < 512; ++hp) acc += tc[c][hp] * attend[(size_t)hp * 512 + h];
      v = fast_tanh(acc);
    }
    a_bf[c * 512 + h] = f2bf(v);
  }
}

// ---------------- GRU recurrence: weight-stationary, agent flags, LDS ready-mask ----------------
// grid 256 = 16 batch-groups x 16 col-groups; 448 threads = 7 waves.
// Waves 0-5 compute; wave 6 polls flags and publishes the 32-bit ready mask to
// LDS (release). Compute threads are PRODUCER-SPECIALIZED (thread t stages only
// producer t&15's slice): spin on the LDS mask for own producer's 2 bits (cheap,
// no fabric traffic), then batch-issue 5-6 u64 agent loads. Early producers'
// slices stage while stragglers' flags are in flight -> B1 barrier deleted,
// staging burst spread out. h-stores issue per-row inside the gate loop so
// store latency hides under gate VALU.
__global__ __launch_bounds__(448) void k_gru(
    const int* __restrict__ seq, const float* __restrict__ embed_W,
    const float* __restrict__ W_ih, const float* __restrict__ W_hh,
    const float* __restrict__ b_ih, const float* __restrict__ b_hh,
    unsigned short* __restrict__ h_ex, unsigned* __restrict__ flags,
    unsigned short* __restrict__ seq_repr,
    const unsigned short* __restrict__ x_pre, int xpre)
{
  __shared__ unsigned short x_lds[2][16][328];   // tanh(emb) bf16, K 300->320 (+8 pad)
  __shared__ unsigned short h_lds[16][520];      // h bf16 for MFMA A-frags
  __shared__ float rz_lds[2][16][32];            // r/z pre-activations
  __shared__ unsigned rdy[2];                    // per-step producer ready masks

  const int tid = threadIdx.x;
  const int w = tid >> 6, l = tid & 63, lo = l & 15, hi = l >> 4;
  const bool cw = (w < 6);                // compute wave?
  const int bid = blockIdx.x;
  const int g_b = (bid & 7) * 2 + (bid >> 7);    // batch group, XCD-clustered
  const int g_c = (bid >> 3) & 15;               // col group

  const int gg = (w < 6) ? (w >> 1) : 0;  // 0=r,1=z,2=n
  const int cb = (w & 1) * 16;
  const int jrow = cw ? (gg * 512 + g_c * 32 + cb + lo) : 0;  // gate row [0,1536)

  // --- weight fragments (persistent in VGPRs; waves 0-5 only) ---
  s16x8 whh[16];
  s16x8 wih[10];
  float bsum = 0.f, bni = 0.f, bnh = 0.f;
  if (cw) {
    #pragma unroll
    for (int kt = 0; kt < 16; ++kt) {
      const float* p = W_hh + (size_t)jrow * 512 + kt * 32 + hi * 8;
      f32x4 a0 = *(const f32x4*)p;
      f32x4 a1 = *(const f32x4*)(p + 4);
      s16x8 v;
      v[0]=(short)f2bf(a0[0]); v[1]=(short)f2bf(a0[1]); v[2]=(short)f2bf(a0[2]); v[3]=(short)f2bf(a0[3]);
      v[4]=(short)f2bf(a1[0]); v[5]=(short)f2bf(a1[1]); v[6]=(short)f2bf(a1[2]); v[7]=(short)f2bf(a1[3]);
      whh[kt] = v;
    }
    #pragma unroll
    for (int kt = 0; kt < 10; ++kt) {
      s16x8 v;
      #pragma unroll
      for (int jj = 0; jj < 8; ++jj) {
        int k = kt * 32 + hi * 8 + jj;
        float f = (k < NE) ? W_ih[(size_t)jrow * NE + k] : 0.f;
        v[jj] = (short)f2bf(f);
      }
      wih[kt] = v;
    }
    bsum = b_ih[jrow] + b_hh[jrow];
    bni = b_ih[jrow]; bnh = b_hh[jrow];
  }

  float hcar[4] = {0.f, 0.f, 0.f, 0.f};   // f32 carry, lane-owned
  const unsigned* flg = flags + g_b * 32;  // 32 half-flags for my batch group

  // x-prefetch task indices for waves 1-5 (xpre path)
  const int xt = tid - 64;                 // 0..319 for waves 1-5
  const bool xw = (w >= 1 && w < 6);
  const int xr0 = xw ? (xt / 40) : 0,          xc0 = xw ? (xt % 40) : 0;
  const int xr1 = xw ? ((xt + 320) / 40) : 0,  xc1 = xw ? ((xt + 320) % 40) : 0;

  // staging specialization: compute thread tid stages producer (tid&15)
  const int sp = tid & 15;                 // my producer
  const int t24 = tid >> 4;                // 0..23 within producer team (cw only)

  auto do_gather = [&](int ss) {          // fallback (cw waves, 384-stride)
    const int buf = ss & 1;
    #pragma unroll
    for (int i = 0; i < 2; ++i) {
      int task = tid + 384 * i;
      if (task < 640) {
        int r = task & 15, grp = task >> 4;
        float vals[8];
        if (grp < 38) {
          int id = seq[(size_t)(g_b * 16 + r) * NS + ss];
          const float* ep = embed_W + (size_t)id * NE;
          if (grp < 37) {
            f32x4 u0 = *(const f32x4*)(ep + grp * 8);
            f32x4 u1 = *(const f32x4*)(ep + grp * 8 + 4);
            vals[0]=u0[0];vals[1]=u0[1];vals[2]=u0[2];vals[3]=u0[3];
            vals[4]=u1[0];vals[5]=u1[1];vals[6]=u1[2];vals[7]=u1[3];
          } else {
            #pragma unroll
            for (int jj = 0; jj < 8; ++jj) { int cc = 296 + jj; vals[jj] = (cc < NE) ? ep[cc] : 0.f; }
          }
        } else {
          #pragma unroll
          for (int jj = 0; jj < 8; ++jj) vals[jj] = 0.f;
        }
        s16x8 pv;
        #pragma unroll
        for (int jj = 0; jj < 8; ++jj) pv[jj] = (short)f2bf(fast_tanh(vals[jj]));
        *(s16x8*)&x_lds[buf][r][grp * 8] = pv;
      }
    }
  };

  if (xpre) {                             // prologue: synchronous fill of x_lds[0]
    if (xw) {
      const unsigned short* src = x_pre + ((size_t)g_b * NS + 0) * (16 * 320);
      s16x8 v0 = *(const s16x8*)(src + xr0 * 320 + xc0 * 8);
      s16x8 v1 = *(const s16x8*)(src + xr1 * 320 + xc1 * 8);
      *(s16x8*)&x_lds[0][xr0][xc0 * 8] = v0;
      *(s16x8*)&x_lds[0][xr1][xc1 * 8] = v1;
    }
  } else if (cw) {
    do_gather(0);
  }
  __syncthreads();                        // x_lds[0] ready for iter-0 ax

  #pragma unroll 1
  for (int s = 0; s < NS; ++s) {
    const bool xpf = xpre && (s + 1 < NS) && xw;
    s16x8 xv0, xv1;
    f32x4 ax_ = {0.f,0.f,0.f,0.f};

    if (cw) {
      // ---- x-prefetch issue (regs; LDS write deferred past B2) ----
      if (xpf) {
        const unsigned short* src = x_pre + ((size_t)g_b * NS + (s + 1)) * (16 * 320);
        xv0 = *(const s16x8*)(src + xr0 * 320 + xc0 * 8);
        xv1 = *(const s16x8*)(src + xr1 * 320 + xc1 * 8);
      } else if (!xpre && s + 1 < NS) {
        do_gather(s + 1);
      }
      // ---- ax: h-independent GEMM ----
      #pragma unroll
      for (int kt = 0; kt < 10; ++kt) {
        s16x8 af = *(const s16x8*)&x_lds[s & 1][lo][kt * 32 + hi * 8];
        ax_ = __builtin_amdgcn_mfma_f32_16x16x32_bf16(af, wih[kt], ax_, 0, 0, 0);
      }
    } else {
      // ---- wave 6: poll flags, publish ready-mask to LDS ----
      if (s > 0) {
        const unsigned* fp = flg + (l & 31);
        int guard = 0; unsigned last = 0;
        for (;;) {
          unsigned f = __hip_atomic_load(fp, __ATOMIC_RELAXED, __HIP_MEMORY_SCOPE_AGENT);
          unsigned m32 = (unsigned)__ballot(f >= (unsigned)s);
          if (l == 0 && m32 != last) {
            __hip_atomic_store(&rdy[s & 1], m32, __ATOMIC_RELEASE, __HIP_MEMORY_SCOPE_WORKGROUP);
            last = m32;
          }
          if (m32 == 0xFFFFFFFFu) break;
          if (++guard > (1 << 12)) {       // never-hang; trip -> absmax fail
            if (l == 0)
              __hip_atomic_store(&rdy[s & 1], 0xFFFFFFFFu, __ATOMIC_RELEASE, __HIP_MEMORY_SCOPE_WORKGROUP);
            break;
          }
        }
      }
    }

    // ---- producer-specialized staging (compute waves only) ----
    if (cw) {
      const unsigned short* hsrc = h_ex + ((size_t)(s & 1) * 16 + g_b) * (16 * 512);
      if (s > 0) {                         // spin on OWN producer's 2 bits (LDS)
        const int p2 = sp * 2;
        int g2 = 0;
        for (;;) {
          unsigned m = __hip_atomic_load(&rdy[s & 1], __ATOMIC_ACQUIRE, __HIP_MEMORY_SCOPE_WORKGROUP);
          if (((m >> p2) & 3u) == 3u) break;
          if (++g2 > (1 << 14)) break;     // never-hang
        }
      }
      unsigned long long hv[6];
      #pragma unroll
      for (int k = 0; k < 6; ++k) {        // batch-issue loads (independent)
        int j = t24 + 24 * k;
        if (j < 128) {
          int r = j >> 3, c4 = sp * 8 + (j & 7);
          hv[k] = __hip_atomic_load(
              (const unsigned long long*)(hsrc + r * 512 + c4 * 4),
              __ATOMIC_RELAXED, __HIP_MEMORY_SCOPE_AGENT);
        }
      }
      #pragma unroll
      for (int k = 0; k < 6; ++k) {
        int j = t24 + 24 * k;
        if (j < 128) {
          int r = j >> 3, c4 = sp * 8 + (j & 7);
          *(unsigned long long*)&h_lds[r][c4 * 4] = hv[k];
        }
      }
    }
    __syncthreads();                      // B2: h_lds complete

    if (!cw) {                            // reset next step's ready word
      if (l == 0)
        __hip_atomic_store(&rdy[(s + 1) & 1], 0u, __ATOMIC_RELAXED, __HIP_MEMORY_SCOPE_WORKGROUP);
    } else {
      // deferred x-prefetch LDS write
      if (xpf) {
        *(s16x8*)&x_lds[(s + 1) & 1][xr0][xc0 * 8] = xv0;
        *(s16x8*)&x_lds[(s + 1) & 1][xr1][xc1 * 8] = xv1;
      }
      // ah: 2 accumulator chains
      f32x4 ah0 = {0.f,0.f,0.f,0.f}, ah1 = {0.f,0.f,0.f,0.f};
      #pragma unroll
      for (int kt = 0; kt < 16; kt += 2) {
        s16x8 af0 = *(const s16x8*)&h_lds[lo][kt * 32 + hi * 8];
        s16x8 af1 = *(const s16x8*)&h_lds[lo][(kt + 1) * 32 + hi * 8];
        ah0 = __builtin_amdgcn_mfma_f32_16x16x32_bf16(af0, whh[kt], ah0, 0, 0, 0);
        ah1 = __builtin_amdgcn_mfma_f32_16x16x32_bf16(af1, whh[kt + 1], ah1, 0, 0, 0);
      }
      f32x4 ah = ah0 + ah1;

      if (w < 4) {                        // r,z: write pre-activations
        #pragma unroll
        for (int j = 0; j < 4; ++j) {
          int row = hi * 4 + j;
          rz_lds[gg][row][cb + lo] = ax_[j] + ah[j] + bsum;
        }
      }
      __syncthreads();                    // B3

      if (w >= 4) {                       // n-gate: per-row compute+store pipeline
        unsigned short* hdst = h_ex + ((size_t)((s + 1) & 1) * 16 + g_b) * (16 * 512);
        const int cpr = cb + lo;
        const int col = g_c * 32 + cpr;
        unsigned words[4];
        #pragma unroll
        for (int j = 0; j < 4; ++j) {
          int row = hi * 4 + j;
          float rr = sigm(rz_lds[0][row][cpr]);
          float zz = sigm(rz_lds[1][row][cpr]);
          float nn = fast_tanh(ax_[j] + bni + rr * (ah[j] + bnh));
          float hn = (1.f - zz) * nn + zz * hcar[j];
          hcar[j] = hn;
          unsigned myb = (unsigned)f2bf(hn);
          unsigned other = __shfl_xor(myb, 1);
          words[j] = myb | (other << 16);
          if ((lo & 1) == 0)              // store THIS row now (hides under next row's VALU)
            __hip_atomic_store((unsigned*)(hdst + row * 512 + col), words[j],
                               __ATOMIC_RELAXED, __HIP_MEMORY_SCOPE_AGENT);
        }
        asm volatile("s_waitcnt vmcnt(0)" ::: "memory");  // drain h stores
        if (l == 0)                       // signal: this n-wave's half done
          __hip_atomic_store((unsigned*)(flags + g_b * 32 + g_c * 2 + (w & 1)),
                             (unsigned)(s + 1),
                             __ATOMIC_RELAXED, __HIP_MEMORY_SCOPE_AGENT);
        if ((lo & 1) == 0) {              // seq_repr writes: in-flight, off-path
          #pragma unroll
          for (int j = 0; j < 4; ++j)
            *(unsigned*)(seq_repr + ((size_t)(g_b * 16 + hi * 4 + j) * NS + s) * NH + col) = words[j];
        }
      }
      continue;
    }
    __syncthreads();                      // B3 (wave 6)
  }
}

// ---------------- attention + logits + log_softmax, one WG per batch row ----------------
__global__ __launch_bounds__(256) void k_attn(const int* __restrict__ seq,
                                              const unsigned short* __restrict__ seq_repr,
                                              const unsigned short* __restrict__ a_bf,
                                              const float* __restrict__ W_cls,
                                              const float* __restrict__ b_cls,
                                              float* __restrict__ out)
{
  __shared__ unsigned short V[32][520];
  __shared__ float P[32][8];
  __shared__ float red[4][12];
  const int tid = threadIdx.x, b = blockIdx.x;
  const int w = tid >> 6, l = tid & 63, lo = l & 15, hi = l >> 4;

  s16x8 afr[16];                          // B-frags of a (class attn vectors)
  #pragma unroll
  for (int kt = 0; kt < 16; ++kt)
    afr[kt] = *(const s16x8*)(a_bf + (size_t)lo * 512 + kt * 32 + hi * 8);

  float ctx0[6] = {0,0,0,0,0,0}, ctx1[6] = {0,0,0,0,0,0};   // h = 2*tid, 2*tid+1
  const unsigned short* vbase = seq_repr + (size_t)b * NS * NH;

  for (int sc = 0; sc < 16; ++sc) {
    #pragma unroll 4
    for (int i = 0; i < 8; ++i) {         // stage 32 x 512 bf16
      int task = tid + 256 * i;
      int sl = task >> 6, grp = task & 63;
      s16x8 v = *(const s16x8*)(vbase + (size_t)(sc * 32 + sl) * NH + grp * 8);
      *(s16x8*)&V[sl][grp * 8] = v;
    }
    __syncthreads();
    if (w < 2) {                          // scores via MFMA: [16 s][6 c]
      f32x4 acc = {0.f,0.f,0.f,0.f};
      int sl0 = w * 16;
      #pragma unroll
      for (int kt = 0; kt < 16; ++kt) {
        s16x8 af = *(const s16x8*)&V[sl0 + lo][kt * 32 + hi * 8];
        acc = __builtin_amdgcn_mfma_f32_16x16x32_bf16(af, afr[kt], acc, 0, 0, 0);
      }
      if (lo < 8) {
        #pragma unroll
        for (int j = 0; j < 4; ++j) {
          int sl = sl0 + hi * 4 + j;
          float p = 0.f;
          if (lo < 6) {
            int s = sc * 32 + sl;
            p = (seq[(size_t)b * NS + s] > 0) ? fast_tanh(acc[j]) : 0.f;
          }
          P[sl][lo] = p;
        }
      }
    }
    __syncthreads();
    #pragma unroll 2
    for (int sl = 0; sl < 32; ++sl) {     // ctx += tanh(score) * V
      unsigned v2 = *(const unsigned*)&V[sl][tid * 2];
      float v0 = bf2f((unsigned short)(v2 & 0xFFFFu));
      float v1 = bf2f((unsigned short)(v2 >> 16));
      #pragma unroll
      for (int c = 0; c < 6; ++c) {
        float p = P[sl][c];
        ctx0[c] += p * v0; ctx1[c] += p * v1;
      }
    }
    __syncthreads();
  }

  // logits + log_softmax
  float pl[12];
  #pragma unroll
  for (int c = 0; c < 6; ++c) {
    float t0 = fast_tanh(ctx0[c]), t1 = fast_tanh(ctx1[c]);
    pl[c * 2 + 0] = t0 * W_cls[tid * 2] + t1 * W_cls[tid * 2 + 1];
    pl[c * 2 + 1] = t0 * W_cls[512 + tid * 2] + t1 * W_cls[512 + tid * 2 + 1];
  }
  #pragma unroll
  for (int i = 0; i < 12; ++i) {
    float v = pl[i];
    for (int off = 32; off > 0; off >>= 1) v += __shfl_down(v, off);
    if (l == 0) red[w][i] = v;
  }
  __syncthreads();
  if (tid < 6) {
    int c = tid;
    float l0 = red[0][c*2] + red[1][c*2] + red[2][c*2] + red[3][c*2] + b_cls[0];
    float l1 = red[0][c*2+1] + red[1][c*2+1] + red[2][c*2+1] + red[3][c*2+1] + b_cls[1];
    float m = fmaxf(l0, l1);
    float lse = m + logf(__expf(l0 - m) + __expf(l1 - m));
    out[c * 512 + b * 2 + 0] = l0 - lse;
    out[c * 512 + b * 2 + 1] = l1 - lse;
  }
}

extern "C" void kernel_launch(void* const* d_in, const int* in_sizes, int n_in,
                              void* d_out, int out_size, void* d_ws, size_t ws_size,
                              hipStream_t stream) {
  const int*   seq      = (const int*)d_in[0];
  const int*   classes  = (const int*)d_in[1];
  const float* embed_W  = (const float*)d_in[2];
  const float* ecw      = (const float*)d_in[3];
  const float* W_ih     = (const float*)d_in[4];
  const float* W_hh     = (const float*)d_in[5];
  const float* b_ih     = (const float*)d_in[6];
  const float* b_hh     = (const float*)d_in[7];
  const float* attend   = (const float*)d_in[8];
  const float* W_cls    = (const float*)d_in[9];
  const float* b_cls    = (const float*)d_in[10];
  float* out = (float*)d_out;

  char* ws = (char*)d_ws;
  const size_t OFF_HEX  = 134217728;                 // after seq_repr
  const size_t OFF_FLG  = OFF_HEX + 524288;
  const size_t OFF_ABF  = OFF_FLG + 16384;
  const size_t OFF_XPRE = OFF_ABF + 16384;
  const size_t XPRE_BYTES = (size_t)16 * NS * 16 * 320 * 2;   // 83,886,080
  unsigned short* seq_repr = (unsigned short*)ws;
  unsigned short* h_ex     = (unsigned short*)(ws + OFF_HEX);
  unsigned*       flags    = (unsigned*)(ws + OFF_FLG);
  unsigned short* a_bf     = (unsigned short*)(ws + OFF_ABF);
  unsigned short* x_pre    = (unsigned short*)(ws + OFF_XPRE);
  const int xpre = (ws_size >= OFF_XPRE + XPRE_BYTES) ? 1 : 0;

  hipLaunchKernelGGL(k_zero, dim3(64), dim3(256), 0, stream, h_ex, flags);
  hipLaunchKernelGGL(k_amat, dim3(8), dim3(256), 0, stream, classes, ecw, attend, a_bf);
  if (xpre)
    hipLaunchKernelGGL(k_xemb, dim3(2048), dim3(256), 0, stream, seq, embed_W, x_pre);
  hipLaunchKernelGGL(k_gru, dim3(256), dim3(448), 0, stream,
                     seq, embed_W, W_ih, W_hh, b_ih, b_hh, h_ex, flags, seq_repr,
                     x_pre, xpre);
  hipLaunchKernelGGL(k_attn, dim3(256), dim3(256), 0, stream,
                     seq, seq_repr, a_bf, W_cls, b_cls, out);
}